// Round 1
// baseline (806.192 us; speedup 1.0000x reference)
//
#include <hip/hip_runtime.h>
#include <math.h>

#define D     512
#define BSZ   16
#define TLEN  16384
#define ROWS  128              // lfb rows per block in k_attn
#define CHUNKS (TLEN / ROWS)   // 128 partials per batch
#define LN_EPS 1e-5f
#define SCALE 22.627416997969522f  // sqrt(512)

typedef float v4 __attribute__((ext_vector_type(4)));

// ---- static scratch (avoids ws_size assumptions; fully rewritten each call
// before any read, all on `stream`, so re-poisoning semantics are satisfied) ----
__device__ float g_theta[BSZ * D];
__device__ float g_u[BSZ * D];
__device__ float g_pm[BSZ * CHUNKS];
__device__ float g_pl[BSZ * CHUNKS];
__device__ float g_pv[(size_t)BSZ * CHUNKS * D];
__device__ float g_ctx[BSZ * D];
__device__ float g_feats[BSZ * 2 * D];
__device__ float g_gact[BSZ * 2 * D];

// ---------- A1: theta[b,d] = x[b] . w_theta[d,:] + b_theta[d] ----------
__global__ __launch_bounds__(256) void k_theta(const float* __restrict__ x,
                                               const float* __restrict__ w_theta,
                                               const float* __restrict__ b_theta) {
  __shared__ float x_sm[D];
  const int b = blockIdx.y, t = threadIdx.x;
  x_sm[t] = x[b * D + t];
  x_sm[t + 256] = x[b * D + t + 256];
  __syncthreads();
  const int d = blockIdx.x * 256 + t;
  const float4* wrow = (const float4*)(w_theta + (size_t)d * D);
  float acc = b_theta[d];
#pragma unroll 8
  for (int e4 = 0; e4 < D / 4; ++e4) {
    float4 w4 = wrow[e4];
    acc += w4.x * x_sm[4 * e4] + w4.y * x_sm[4 * e4 + 1] +
           w4.z * x_sm[4 * e4 + 2] + w4.w * x_sm[4 * e4 + 3];
  }
  g_theta[b * D + d] = acc;
}

// ---------- A2: u[b,e] = scale * sum_d theta[b,d] * w_phi[d,e] ----------
__global__ __launch_bounds__(256) void k_u(const float* __restrict__ w_phi) {
  __shared__ float th_sm[D];
  const int b = blockIdx.y, t = threadIdx.x;
  th_sm[t] = g_theta[b * D + t];
  th_sm[t + 256] = g_theta[b * D + t + 256];
  __syncthreads();
  const int e = blockIdx.x * 256 + t;
  float acc = 0.f;
#pragma unroll 8
  for (int d = 0; d < D; ++d) acc += th_sm[d] * w_phi[(size_t)d * D + e];
  g_u[b * D + e] = acc * SCALE;
}

// ---------- B: single-pass online-softmax over lfb rows ----------
// score[t] = u[b] . lfb[b,t,:]; accumulate v = sum softmax-weighted rows.
__global__ __launch_bounds__(256) void k_attn(const float* __restrict__ lfb) {
  const int b = blockIdx.y, chunk = blockIdx.x;
  const int tid = threadIdx.x, lane = tid & 63, wave = tid >> 6;

  const v4* urow = (const v4*)(g_u + b * D);
  const v4 u0 = urow[lane];
  const v4 u1 = urow[64 + lane];

  float m = -INFINITY, l = 0.f;
  v4 va = {0.f, 0.f, 0.f, 0.f};
  v4 vb = {0.f, 0.f, 0.f, 0.f};

  const float* base = lfb + ((size_t)b * TLEN + (size_t)chunk * ROWS) * D;
  for (int i = 0; i < ROWS / 4; ++i) {
    const v4* row = (const v4*)(base + (size_t)(i * 4 + wave) * D);
    v4 a = __builtin_nontemporal_load(row + lane);
    v4 c = __builtin_nontemporal_load(row + 64 + lane);
    v4 p = a * u0 + c * u1;
    float s = p.x + p.y + p.z + p.w;
#pragma unroll
    for (int off = 32; off > 0; off >>= 1) s += __shfl_xor(s, off);
    if (s > m) {           // wave-uniform branch: no divergence
      float alpha = __expf(m - s);   // first iter: exp(-inf)=0 zeroes init state
      l = l * alpha + 1.f;
      va = va * alpha + a;
      vb = vb * alpha + c;
      m = s;
    } else {
      float w = __expf(s - m);
      l += w;
      va += a * w;
      vb += c * w;
    }
  }

  __shared__ float wm[4], wl[4];
  __shared__ float wv[4][D];
  ((v4*)wv[wave])[lane] = va;
  ((v4*)wv[wave])[64 + lane] = vb;
  if (lane == 0) { wm[wave] = m; wl[wave] = l; }
  __syncthreads();

  const float bm = fmaxf(fmaxf(wm[0], wm[1]), fmaxf(wm[2], wm[3]));
  const float f0 = __expf(wm[0] - bm), f1 = __expf(wm[1] - bm);
  const float f2 = __expf(wm[2] - bm), f3 = __expf(wm[3] - bm);
  const size_t pidx = (size_t)b * CHUNKS + chunk;
#pragma unroll
  for (int k = 0; k < 2; ++k) {
    int p = tid + k * 256;
    g_pv[pidx * D + p] =
        f0 * wv[0][p] + f1 * wv[1][p] + f2 * wv[2][p] + f3 * wv[3][p];
  }
  if (tid == 0) {
    g_pm[pidx] = bm;
    g_pl[pidx] = f0 * wl[0] + f1 * wl[1] + f2 * wl[2] + f3 * wl[3];
  }
}

// ---------- C1: combine partials, ctx = W_gi (v/l) + b_gi ----------
__global__ __launch_bounds__(256) void k_ctx(const float* __restrict__ w_gi,
                                             const float* __restrict__ b_gi) {
  __shared__ float v_sm[D];
  const int b = blockIdx.y, t = threadIdx.x;
  const float* pm = g_pm + b * CHUNKS;
  const float* pl = g_pl + b * CHUNKS;
  const float* pv = g_pv + (size_t)b * CHUNKS * D;
  float bm = -INFINITY;
  for (int c = 0; c < CHUNKS; ++c) bm = fmaxf(bm, pm[c]);
  float lg = 0.f, a0 = 0.f, a1 = 0.f;
  for (int c = 0; c < CHUNKS; ++c) {
    float f = __expf(pm[c] - bm);
    lg += f * pl[c];
    a0 += f * pv[(size_t)c * D + t];
    a1 += f * pv[(size_t)c * D + t + 256];
  }
  const float invl = 1.f / lg;
  v_sm[t] = a0 * invl;
  v_sm[t + 256] = a1 * invl;
  __syncthreads();
  const int d = blockIdx.x * 256 + t;
  const float4* wrow = (const float4*)(w_gi + (size_t)d * D);
  float acc = b_gi[d];
#pragma unroll 8
  for (int e4 = 0; e4 < D / 4; ++e4) {
    float4 w4 = wrow[e4];
    acc += w4.x * v_sm[4 * e4] + w4.y * v_sm[4 * e4 + 1] +
           w4.z * v_sm[4 * e4 + 2] + w4.w * v_sm[4 * e4 + 3];
  }
  g_ctx[b * D + d] = acc;
}

// ---------- C2: h = relu(LN(ctx)); fc; feats = [x, h@w_fc.T+b_fc+x] ----------
__global__ __launch_bounds__(256) void k_lnfc(const float* __restrict__ ln_g,
                                              const float* __restrict__ ln_b,
                                              const float* __restrict__ w_fc,
                                              const float* __restrict__ b_fc,
                                              const float* __restrict__ x) {
  __shared__ float h_sm[D];
  __shared__ float rs[4], rq[4];
  const int b = blockIdx.y, t = threadIdx.x;
  const float c0 = g_ctx[b * D + t], c1 = g_ctx[b * D + t + 256];
  float s = c0 + c1, sq = c0 * c0 + c1 * c1;
#pragma unroll
  for (int off = 32; off > 0; off >>= 1) {
    s += __shfl_xor(s, off);
    sq += __shfl_xor(sq, off);
  }
  if ((t & 63) == 0) { rs[t >> 6] = s; rq[t >> 6] = sq; }
  __syncthreads();
  const float mu = (rs[0] + rs[1] + rs[2] + rs[3]) * (1.f / D);
  const float var = (rq[0] + rq[1] + rq[2] + rq[3]) * (1.f / D) - mu * mu;
  const float rstd = rsqrtf(var + LN_EPS);
  h_sm[t] = fmaxf((c0 - mu) * rstd * ln_g[t] + ln_b[t], 0.f);
  h_sm[t + 256] = fmaxf((c1 - mu) * rstd * ln_g[t + 256] + ln_b[t + 256], 0.f);
  __syncthreads();
  const int d = blockIdx.x * 256 + t;
  const float4* wrow = (const float4*)(w_fc + (size_t)d * D);
  float acc = b_fc[d];
#pragma unroll 8
  for (int e4 = 0; e4 < D / 4; ++e4) {
    float4 w4 = wrow[e4];
    acc += w4.x * h_sm[4 * e4] + w4.y * h_sm[4 * e4 + 1] +
           w4.z * h_sm[4 * e4 + 2] + w4.w * h_sm[4 * e4 + 3];
  }
  const float xv = x[b * D + d];
  g_feats[(size_t)b * 2 * D + d] = xv;
  g_feats[(size_t)b * 2 * D + D + d] = acc + xv;   // longterm = fc(h) + x
}

// ---------- C3: g = relu(relu(feats) @ w_nlb.T + b_nlb) ----------
__global__ __launch_bounds__(256) void k_nlb(const float* __restrict__ w_nlb,
                                             const float* __restrict__ b_nlb) {
  __shared__ float f_sm[2 * D];
  const int b = blockIdx.y, t = threadIdx.x;
#pragma unroll
  for (int k = 0; k < 4; ++k)
    f_sm[t + k * 256] = fmaxf(g_feats[(size_t)b * 2 * D + t + k * 256], 0.f);
  __syncthreads();
  const int j = blockIdx.x * 256 + t;
  const float4* wrow = (const float4*)(w_nlb + (size_t)j * 2 * D);
  float acc = b_nlb[j];
#pragma unroll 8
  for (int e4 = 0; e4 < 2 * D / 4; ++e4) {
    float4 w4 = wrow[e4];
    acc += w4.x * f_sm[4 * e4] + w4.y * f_sm[4 * e4 + 1] +
           w4.z * f_sm[4 * e4 + 2] + w4.w * f_sm[4 * e4 + 3];
  }
  g_gact[(size_t)b * 2 * D + j] = fmaxf(acc, 0.f);
}

// ---------- C4: preds ----------
__global__ __launch_bounds__(256) void k_pred(const float* __restrict__ w1,
                                              const float* __restrict__ b1,
                                              const float* __restrict__ w2,
                                              const float* __restrict__ b2,
                                              float* __restrict__ out) {
  __shared__ float rs[4], rq[4];
  const int b = blockIdx.x, t = threadIdx.x;
  const float* gb = g_gact + (size_t)b * 2 * D;
  float p1 = gb[t] * w1[t] + gb[t + 256] * w1[t + 256];
  float p2 = gb[D + t] * w2[t] + gb[D + t + 256] * w2[t + 256];
#pragma unroll
  for (int off = 32; off > 0; off >>= 1) {
    p1 += __shfl_xor(p1, off);
    p2 += __shfl_xor(p2, off);
  }
  if ((t & 63) == 0) { rs[t >> 6] = p1; rq[t >> 6] = p2; }
  __syncthreads();
  if (t == 0) {
    out[b * 2 + 0] = rs[0] + rs[1] + rs[2] + rs[3] + b1[0];
    out[b * 2 + 1] = rq[0] + rq[1] + rq[2] + rq[3] + b2[0];
  }
}

extern "C" void kernel_launch(void* const* d_in, const int* in_sizes, int n_in,
                              void* d_out, int out_size, void* d_ws,
                              size_t ws_size, hipStream_t stream) {
  const float* x       = (const float*)d_in[0];
  const float* lfb     = (const float*)d_in[1];
  const float* w_theta = (const float*)d_in[2];
  const float* b_theta = (const float*)d_in[3];
  const float* w_phi   = (const float*)d_in[4];
  // d_in[5] = b_phi: adds a per-batch constant to scores -> cancels in softmax
  const float* w_gi    = (const float*)d_in[6];
  const float* b_gi    = (const float*)d_in[7];
  const float* ln_g    = (const float*)d_in[8];
  const float* ln_b    = (const float*)d_in[9];
  const float* w_fc    = (const float*)d_in[10];
  const float* b_fc    = (const float*)d_in[11];
  const float* w_nlb   = (const float*)d_in[12];
  const float* b_nlb   = (const float*)d_in[13];
  const float* w1      = (const float*)d_in[14];
  const float* b1      = (const float*)d_in[15];
  const float* w2      = (const float*)d_in[16];
  const float* b2      = (const float*)d_in[17];
  float* out = (float*)d_out;

  k_theta<<<dim3(2, BSZ), 256, 0, stream>>>(x, w_theta, b_theta);
  k_u<<<dim3(2, BSZ), 256, 0, stream>>>(w_phi);
  k_attn<<<dim3(CHUNKS, BSZ), 256, 0, stream>>>(lfb);
  k_ctx<<<dim3(2, BSZ), 256, 0, stream>>>(w_gi, b_gi);
  k_lnfc<<<dim3(2, BSZ), 256, 0, stream>>>(ln_g, ln_b, w_fc, b_fc, x);
  k_nlb<<<dim3(4, BSZ), 256, 0, stream>>>(w_nlb, b_nlb);
  k_pred<<<BSZ, 256, 0, stream>>>(w1, b1, w2, b2, out);
}